// Round 1
// baseline (47.788 us; speedup 1.0000x reference)
//
#include <hip/hip_runtime.h>
#include <math.h>

// Problem constants (from reference setup_inputs)
#define N_WAY 64
#define N_SUP 16
#define N_QRY 64
#define DIM   1024
#define N_QUERIES (N_WAY * N_QRY)      // 4096
#define ROWS_PER_WAY (N_SUP + N_QRY)   // 80

// Kernel B tiling
#define QT 16     // queries per block
#define KC 128    // K-chunk

// ---------------------------------------------------------------------------
// Kernel A: prototypes (mean of support rows) + ||p||^2 per way.
// grid = 64 (one block per way), block = 256 threads (each owns one float4 of d)
// Also zero-initializes the global accumulators (stream order protects kernel B).
// ---------------------------------------------------------------------------
__global__ __launch_bounds__(256) void proto_kernel(
    const float* __restrict__ x, float* __restrict__ proto,
    float* __restrict__ pnorm, float* __restrict__ accs) {
  const int w = blockIdx.x;
  const int t = threadIdx.x;
  const float4* x4 = (const float4*)x;
  const int base = w * ROWS_PER_WAY * (DIM / 4);  // float4 units
  float4 a = make_float4(0.f, 0.f, 0.f, 0.f);
  #pragma unroll
  for (int s = 0; s < N_SUP; ++s) {
    float4 v = x4[base + s * (DIM / 4) + t];
    a.x += v.x; a.y += v.y; a.z += v.z; a.w += v.w;
  }
  const float inv = 1.0f / (float)N_SUP;
  a.x *= inv; a.y *= inv; a.z *= inv; a.w *= inv;
  ((float4*)proto)[w * (DIM / 4) + t] = a;

  float p = a.x * a.x + a.y * a.y + a.z * a.z + a.w * a.w;
  // block reduce (4 waves of 64)
  __shared__ float red[4];
  for (int off = 32; off > 0; off >>= 1) p += __shfl_down(p, off);
  if ((t & 63) == 0) red[t >> 6] = p;
  __syncthreads();
  if (t == 0) {
    pnorm[w] = red[0] + red[1] + red[2] + red[3];
    if (w == 0) { accs[0] = 0.f; accs[1] = 0.f; }
  }
}

// ---------------------------------------------------------------------------
// Kernel B: surrogate logits s[n,w] = 2*dot(q_n, p_w) - ||p_w||^2, fused
// log-softmax + argmax + per-label logp, block-level partial loss/correct,
// one atomicAdd pair per block.
// grid = 4096/QT = 256, block = 256.
// ---------------------------------------------------------------------------
__global__ __launch_bounds__(256) void main_kernel(
    const float* __restrict__ x, const float* __restrict__ proto,
    const float* __restrict__ pnorm, float* __restrict__ accs) {
  __shared__ float A[KC][QT + 2];   // [k][q], pad to 18 (8B-aligned float2 rows)
  __shared__ float B[KC][N_WAY + 2];// [k][w], pad to 66
  __shared__ float S[QT][N_WAY + 1];// logits staging, pad 65

  const int tid = threadIdx.x;
  const int qg = tid >> 5;   // 0..7  -> q0 = qg*2
  const int wg = tid & 31;   // 0..31 -> w0 = wg*2
  const int qb = blockIdx.x * QT;  // query tile base (all in same way: QT|64)

  float acc00 = 0.f, acc01 = 0.f, acc10 = 0.f, acc11 = 0.f;

  for (int kc = 0; kc < DIM; kc += KC) {
    __syncthreads();
    // stage A: QT rows x KC k = 512 float4, 2 per thread (coalesced loads)
    #pragma unroll
    for (int r = 0; r < 2; ++r) {
      int i = tid + 256 * r;
      int q = i >> 5;        // 0..15
      int k4 = i & 31;       // 0..31 (float4 index within chunk)
      int n = qb + q;
      int row = (n >> 6) * ROWS_PER_WAY + N_SUP + (n & 63);
      float4 v = *(const float4*)(x + row * DIM + kc + k4 * 4);
      int kk = k4 * 4;
      A[kk + 0][q] = v.x; A[kk + 1][q] = v.y;
      A[kk + 2][q] = v.z; A[kk + 3][q] = v.w;
    }
    // stage B: 64 ways x KC k = 2048 float4, 8 per thread (coalesced loads)
    #pragma unroll
    for (int r = 0; r < 8; ++r) {
      int i = tid + 256 * r;
      int w = i >> 5;        // 0..63
      int k4 = i & 31;
      float4 v = *(const float4*)(proto + w * DIM + kc + k4 * 4);
      int kk = k4 * 4;
      B[kk + 0][w] = v.x; B[kk + 1][w] = v.y;
      B[kk + 2][w] = v.z; B[kk + 3][w] = v.w;
    }
    __syncthreads();

    const int q0 = qg * 2, w0 = wg * 2;
    #pragma unroll 8
    for (int k = 0; k < KC; ++k) {
      float a0 = A[k][q0], a1 = A[k][q0 + 1];
      float b0 = B[k][w0], b1 = B[k][w0 + 1];
      acc00 += a0 * b0; acc01 += a0 * b1;
      acc10 += a1 * b0; acc11 += a1 * b1;
    }
  }

  __syncthreads();
  {
    const int q0 = qg * 2, w0 = wg * 2;
    const float pn0 = pnorm[w0], pn1 = pnorm[w0 + 1];
    S[q0][w0]     = 2.f * acc00 - pn0;
    S[q0][w0 + 1] = 2.f * acc01 - pn1;
    S[q0 + 1][w0]     = 2.f * acc10 - pn0;
    S[q0 + 1][w0 + 1] = 2.f * acc11 - pn1;
  }
  __syncthreads();

  // per-query softmax/argmax: wave 0 only, lanes 0..15 do real work
  if (tid < 64) {
    float lossq = 0.f, corr = 0.f;
    if (tid < QT) {
      const int n = qb + tid;
      const int label = n >> 6;
      float m = -INFINITY; int arg = 0;
      #pragma unroll
      for (int w = 0; w < N_WAY; ++w) {
        float v = S[tid][w];
        if (v > m) { m = v; arg = w; }
      }
      float sum = 0.f;
      #pragma unroll
      for (int w = 0; w < N_WAY; ++w) sum += expf(S[tid][w] - m);
      lossq = m + logf(sum) - S[tid][label];
      corr = (arg == label) ? 1.f : 0.f;
    }
    for (int off = 32; off > 0; off >>= 1) {
      lossq += __shfl_down(lossq, off);
      corr  += __shfl_down(corr, off);
    }
    if (tid == 0) {
      atomicAdd(&accs[0], lossq);
      atomicAdd(&accs[1], corr);
    }
  }
}

// ---------------------------------------------------------------------------
// Kernel C: finalize scalars
// ---------------------------------------------------------------------------
__global__ void finalize_kernel(const float* __restrict__ accs,
                                float* __restrict__ out) {
  out[0] = accs[0] * (1.0f / (float)N_QUERIES);
  out[1] = accs[1] * (100.0f / (float)N_QUERIES);
}

extern "C" void kernel_launch(void* const* d_in, const int* in_sizes, int n_in,
                              void* d_out, int out_size, void* d_ws, size_t ws_size,
                              hipStream_t stream) {
  (void)in_sizes; (void)n_in; (void)out_size; (void)ws_size;
  const float* x = (const float*)d_in[0];
  float* out = (float*)d_out;

  float* wsf   = (float*)d_ws;
  float* proto = wsf;                       // 64*1024 floats
  float* pnorm = wsf + N_WAY * DIM;         // 64 floats
  float* accs  = wsf + N_WAY * DIM + N_WAY; // 2 floats

  hipLaunchKernelGGL(proto_kernel, dim3(N_WAY), dim3(256), 0, stream,
                     x, proto, pnorm, accs);
  hipLaunchKernelGGL(main_kernel, dim3(N_QUERIES / QT), dim3(256), 0, stream,
                     x, proto, pnorm, accs);
  hipLaunchKernelGGL(finalize_kernel, dim3(1), dim3(1), 0, stream,
                     accs, out);
}

// Round 2
// 33.780 us; speedup vs baseline: 1.4147x; 1.4147x over previous
//
#include <hip/hip_runtime.h>
#include <math.h>

#define N_WAY 64
#define N_SUP 16
#define N_QRY 64
#define DIM   1024
#define N_QUERIES (N_WAY * N_QRY)      // 4096
#define ROWS_PER_WAY (N_SUP + N_QRY)   // 80
#define QT 16                          // queries per gemm block
#define GEMM_BLOCKS (N_QUERIES / QT)   // 256

typedef __attribute__((ext_vector_type(8))) short short8;
typedef __attribute__((ext_vector_type(4))) float f32x4;

// bf16 round-to-nearest-even from f32 bits
__device__ __forceinline__ unsigned bf16_rne(float f) {
  unsigned u = __float_as_uint(f);
  return (u + 0x7fffu + ((u >> 16) & 1u)) >> 16;
}

// ---------------------------------------------------------------------------
// Kernel A: prototypes (mean of 16 support rows) -> bf16 hi/lo split + ||p||^2.
// grid = 64 (one block per way), block = 256 (thread t owns float4 column t).
// Also zero-initializes accs + ticket (stream order protects the gemm kernel).
// ---------------------------------------------------------------------------
__global__ __launch_bounds__(256) void proto_kernel(
    const float* __restrict__ x, unsigned short* __restrict__ phi,
    unsigned short* __restrict__ plo, float* __restrict__ pnorm,
    float* __restrict__ accs, unsigned* __restrict__ cnt) {
  const int w = blockIdx.x;
  const int t = threadIdx.x;            // float4 column index, 0..255
  const float4* x4 = (const float4*)x;
  const int base = w * ROWS_PER_WAY * (DIM / 4);
  float4 a = make_float4(0.f, 0.f, 0.f, 0.f);
  #pragma unroll
  for (int s = 0; s < N_SUP; ++s) {
    float4 v = x4[base + s * (DIM / 4) + t];
    a.x += v.x; a.y += v.y; a.z += v.z; a.w += v.w;
  }
  const float inv = 1.0f / (float)N_SUP;
  a.x *= inv; a.y *= inv; a.z *= inv; a.w *= inv;

  // split to bf16 hi/lo
  float vals[4] = {a.x, a.y, a.z, a.w};
  unsigned short hh[4], ll[4];
  #pragma unroll
  for (int j = 0; j < 4; ++j) {
    unsigned hb = bf16_rne(vals[j]);
    hh[j] = (unsigned short)hb;
    float r = vals[j] - __uint_as_float(hb << 16);
    ll[j] = (unsigned short)bf16_rne(r);
  }
  *(ushort4*)(phi + w * DIM + 4 * t) = make_ushort4(hh[0], hh[1], hh[2], hh[3]);
  *(ushort4*)(plo + w * DIM + 4 * t) = make_ushort4(ll[0], ll[1], ll[2], ll[3]);

  // ||p||^2 (exact f32 proto) via block reduce
  float p = a.x * a.x + a.y * a.y + a.z * a.z + a.w * a.w;
  __shared__ float red[4];
  for (int off = 32; off > 0; off >>= 1) p += __shfl_down(p, off);
  if ((t & 63) == 0) red[t >> 6] = p;
  __syncthreads();
  if (t == 0) {
    pnorm[w] = red[0] + red[1] + red[2] + red[3];
    if (w == 0) { accs[0] = 0.f; accs[1] = 0.f; *cnt = 0u; }
  }
}

// ---------------------------------------------------------------------------
// Kernel B: split-bf16 MFMA gemm, S[q][w] = 2*q.p - ||p||^2, fused softmax,
// fused finalize via atomic ticket.
// grid = 256, block = 512 (8 waves). Wave v owns K-range [v*128, v*128+128).
// Fragments loaded straight from global: A lane layout (m = lane&15,
// k = (lane>>4)*8 + j), B identical with n = lane&15 (protos stored [w][k]).
// ---------------------------------------------------------------------------
__global__ __launch_bounds__(512) void gemm_kernel(
    const float* __restrict__ x, const unsigned short* __restrict__ phi,
    const unsigned short* __restrict__ plo, const float* __restrict__ pnorm,
    float* __restrict__ accs, unsigned* __restrict__ cnt,
    float* __restrict__ out) {
  __shared__ float Sp[8][16][68];   // per-wave partial tiles (padded)
  __shared__ float So[16][68];      // reduced logits

  const int tid  = threadIdx.x;
  const int wv   = tid >> 6;        // 0..7, K-slice owner
  const int lane = tid & 63;
  const int lrow = lane & 15;       // m (query) / n (way) row within tile
  const int kgrp = lane >> 4;       // 0..3
  const int qb   = blockIdx.x * QT; // all 16 queries share one way-block

  f32x4 acc[4];
  #pragma unroll
  for (int t = 0; t < 4; ++t) acc[t] = (f32x4){0.f, 0.f, 0.f, 0.f};

  // global row of this lane's query
  const int qrow = (qb >> 6) * ROWS_PER_WAY + N_SUP + (qb & 63) + lrow;
  const float* arow = x + (size_t)qrow * DIM;
  const int kbase = wv * 128 + kgrp * 8;

  #pragma unroll
  for (int s = 0; s < 4; ++s) {
    const int k0 = kbase + s * 32;
    // A fragment: 8 consecutive f32, convert to bf16 hi/lo
    f32x4 a0 = *(const f32x4*)(arow + k0);
    f32x4 a1 = *(const f32x4*)(arow + k0 + 4);
    float av[8] = {a0[0], a0[1], a0[2], a0[3], a1[0], a1[1], a1[2], a1[3]};
    short8 ah, al;
    #pragma unroll
    for (int j = 0; j < 8; ++j) {
      unsigned hb = bf16_rne(av[j]);
      ah[j] = (short)hb;
      float r = av[j] - __uint_as_float(hb << 16);
      al[j] = (short)bf16_rne(r);
    }
    // B fragments: 4 way-tiles, hi+lo, straight from global (L1/L2-hot)
    const unsigned short* bh = phi + lrow * DIM + k0;
    const unsigned short* bl = plo + lrow * DIM + k0;
    #pragma unroll
    for (int t = 0; t < 4; ++t) {
      short8 bhv = *(const short8*)(bh + t * 16 * DIM);
      short8 blv = *(const short8*)(bl + t * 16 * DIM);
      acc[t] = __builtin_amdgcn_mfma_f32_16x16x32_bf16(ah, bhv, acc[t], 0, 0, 0);
      acc[t] = __builtin_amdgcn_mfma_f32_16x16x32_bf16(ah, blv, acc[t], 0, 0, 0);
      acc[t] = __builtin_amdgcn_mfma_f32_16x16x32_bf16(al, bhv, acc[t], 0, 0, 0);
    }
  }

  // write per-wave partials: C/D layout col = lane&15, row = (lane>>4)*4 + r
  #pragma unroll
  for (int t = 0; t < 4; ++t)
    #pragma unroll
    for (int r = 0; r < 4; ++r)
      Sp[wv][kgrp * 4 + r][t * 16 + lrow] = acc[t][r];
  __syncthreads();

  // reduce 8 K-slices, apply 2*dot - pnorm
  for (int i = tid; i < QT * N_WAY; i += 512) {
    int q = i >> 6, w = i & 63;
    float s = 0.f;
    #pragma unroll
    for (int v = 0; v < 8; ++v) s += Sp[v][q][w];
    So[q][w] = 2.f * s - pnorm[w];
  }
  __syncthreads();

  // fused log-softmax + argmax (wave 0; lanes 0..15 own one query each)
  if (tid < 64) {
    float lossq = 0.f, corr = 0.f;
    if (tid < QT) {
      const int label = qb >> 6;
      float m = -INFINITY; int arg = 0;
      #pragma unroll
      for (int w = 0; w < N_WAY; ++w) {
        float v = So[tid][w];
        if (v > m) { m = v; arg = w; }
      }
      float sum = 0.f;
      #pragma unroll
      for (int w = 0; w < N_WAY; ++w) sum += expf(So[tid][w] - m);
      lossq = m + logf(sum) - So[tid][label];
      corr = (arg == label) ? 1.f : 0.f;
    }
    for (int off = 32; off > 0; off >>= 1) {
      lossq += __shfl_down(lossq, off);
      corr  += __shfl_down(corr, off);
    }
    if (tid == 0) {
      atomicAdd(&accs[0], lossq);
      atomicAdd(&accs[1], corr);
      __threadfence();
      unsigned old = atomicAdd(cnt, 1u);
      if (old == (unsigned)(gridDim.x - 1)) {  // last block finalizes
        float l = atomicAdd(&accs[0], 0.0f);
        float c = atomicAdd(&accs[1], 0.0f);
        out[0] = l * (1.0f / (float)N_QUERIES);
        out[1] = c * (100.0f / (float)N_QUERIES);
      }
    }
  }
}

extern "C" void kernel_launch(void* const* d_in, const int* in_sizes, int n_in,
                              void* d_out, int out_size, void* d_ws, size_t ws_size,
                              hipStream_t stream) {
  (void)in_sizes; (void)n_in; (void)out_size; (void)ws_size;
  const float* x = (const float*)d_in[0];
  float* out = (float*)d_out;

  // ws layout
  unsigned short* phi = (unsigned short*)d_ws;                  // 64*1024 u16
  unsigned short* plo = phi + N_WAY * DIM;                      // 64*1024 u16
  float* pnorm = (float*)(plo + N_WAY * DIM);                   // 64 f32
  float* accs  = pnorm + N_WAY;                                 // 2 f32
  unsigned* cnt = (unsigned*)(accs + 2);                        // 1 u32

  hipLaunchKernelGGL(proto_kernel, dim3(N_WAY), dim3(256), 0, stream,
                     x, phi, plo, pnorm, accs, cnt);
  hipLaunchKernelGGL(gemm_kernel, dim3(GEMM_BLOCKS), dim3(512), 0, stream,
                     x, phi, plo, pnorm, accs, cnt, out);
}

// Round 3
// 27.815 us; speedup vs baseline: 1.7181x; 1.2144x over previous
//
#include <hip/hip_runtime.h>
#include <math.h>

#define N_WAY 64
#define N_SUP 16
#define N_QRY 64
#define DIM   1024
#define N_QUERIES (N_WAY * N_QRY)      // 4096
#define ROWS_PER_WAY (N_SUP + N_QRY)   // 80
#define QT 16                          // queries per gemm block
#define GEMM_BLOCKS (N_QUERIES / QT)   // 256

typedef __attribute__((ext_vector_type(8))) short short8;
typedef __attribute__((ext_vector_type(4))) float f32x4;

// Truncation split: a ~= hi + lo, hi/lo bf16 (error ~2^-14 relative)
__device__ __forceinline__ void split_trunc(float v, short& hi, short& lo) {
  unsigned u = __float_as_uint(v);
  float hf = __uint_as_float(u & 0xffff0000u);
  hi = (short)(u >> 16);
  float r = v - hf;
  lo = (short)(__float_as_uint(r) >> 16);
}

// Packed B-fragment index (in short8 units) for 32-k block kb, way-tile t:
// a wave reads short8[ (kb*4 + t)*64 + lane ] -- fully coalesced 1KB.
// Element semantics: lane = kgrp*16 + n holds ways n, k = kb*32 + kgrp*8 + j.

// ---------------------------------------------------------------------------
// Kernel A: prototypes (mean of 16 support rows) -> packed bf16 hi/lo
// fragments + ||p||^2. grid = 64 (one block per way), block = 256
// (thread t owns float4 column 4t..4t+3). Zero-inits accs/ticket.
// ---------------------------------------------------------------------------
__global__ __launch_bounds__(256) void proto_kernel(
    const float* __restrict__ x, unsigned short* __restrict__ phi,
    unsigned short* __restrict__ plo, float* __restrict__ pnorm,
    float* __restrict__ accs, unsigned* __restrict__ cnt) {
  const int w = blockIdx.x;
  const int t = threadIdx.x;            // float4 column index, 0..255
  const float4* x4 = (const float4*)x;
  const int base = w * ROWS_PER_WAY * (DIM / 4);
  float4 a = make_float4(0.f, 0.f, 0.f, 0.f);
  #pragma unroll
  for (int s = 0; s < N_SUP; ++s) {
    float4 v = x4[base + s * (DIM / 4) + t];
    a.x += v.x; a.y += v.y; a.z += v.z; a.w += v.w;
  }
  const float inv = 1.0f / (float)N_SUP;
  a.x *= inv; a.y *= inv; a.z *= inv; a.w *= inv;

  // split to bf16 hi/lo, write in packed fragment layout
  float vals[4] = {a.x, a.y, a.z, a.w};
  short hh[4], ll[4];
  #pragma unroll
  for (int j = 0; j < 4; ++j) split_trunc(vals[j], hh[j], ll[j]);

  const int kb   = t >> 3;          // 32-k block of k0 = 4t
  const int kgrp = (t >> 1) & 3;
  const int j0   = (t & 1) * 4;
  const int tile = w >> 4;
  const int lane = kgrp * 16 + (w & 15);
  const int uidx = ((kb * 4 + tile) * 64 + lane) * 8 + j0;
  *(ushort4*)(phi + uidx) = make_ushort4((unsigned short)hh[0], (unsigned short)hh[1],
                                         (unsigned short)hh[2], (unsigned short)hh[3]);
  *(ushort4*)(plo + uidx) = make_ushort4((unsigned short)ll[0], (unsigned short)ll[1],
                                         (unsigned short)ll[2], (unsigned short)ll[3]);

  // ||p||^2 (exact f32 proto) via block reduce
  float p = a.x * a.x + a.y * a.y + a.z * a.z + a.w * a.w;
  __shared__ float red[4];
  for (int off = 32; off > 0; off >>= 1) p += __shfl_down(p, off);
  if ((t & 63) == 0) red[t >> 6] = p;
  __syncthreads();
  if (t == 0) {
    pnorm[w] = red[0] + red[1] + red[2] + red[3];
    if (w == 0) { accs[0] = 0.f; accs[1] = 0.f; *cnt = 0u; }
  }
}

// ---------------------------------------------------------------------------
// Kernel B: split-bf16 MFMA gemm, S[q][w] = 2*q.p - ||p||^2, fused softmax,
// fused finalize via atomic ticket.
// grid = 256, block = 512 (8 waves). Wave wv owns K-range [wv*128, wv*128+128).
// A frags converted in-register from global f32; B frags are packed coalesced.
// ---------------------------------------------------------------------------
__global__ __launch_bounds__(512) void gemm_kernel(
    const float* __restrict__ x, const unsigned short* __restrict__ phi,
    const unsigned short* __restrict__ plo, const float* __restrict__ pnorm,
    float* __restrict__ accs, unsigned* __restrict__ cnt,
    float* __restrict__ out) {
  __shared__ float Sp[8][16][68];   // per-wave partial tiles (padded)
  __shared__ float So[16][68];      // reduced logits

  const int tid  = threadIdx.x;
  const int wv   = tid >> 6;        // 0..7, K-slice owner
  const int lane = tid & 63;
  const int lrow = lane & 15;       // m (query row within tile)
  const int kgrp = lane >> 4;       // 0..3
  const int qb   = blockIdx.x * QT; // all 16 queries share one way

  f32x4 acc[4];
  #pragma unroll
  for (int t = 0; t < 4; ++t) acc[t] = (f32x4){0.f, 0.f, 0.f, 0.f};

  const int qrow = (qb >> 6) * ROWS_PER_WAY + N_SUP + (qb & 63) + lrow;
  const float* arow = x + (size_t)qrow * DIM + kgrp * 8;
  const short8* bhp = (const short8*)phi + lane;
  const short8* blp = (const short8*)plo + lane;

  #pragma unroll
  for (int s = 0; s < 4; ++s) {
    const int kb = wv * 4 + s;              // global 32-k block
    // A fragment: 8 consecutive f32 at k = kb*32 + kgrp*8, truncation split
    f32x4 a0 = *(const f32x4*)(arow + kb * 32);
    f32x4 a1 = *(const f32x4*)(arow + kb * 32 + 4);
    short8 ah, al;
    #pragma unroll
    for (int j = 0; j < 4; ++j) {
      short h, l;
      split_trunc(a0[j], h, l); ah[j] = h; al[j] = l;
      split_trunc(a1[j], h, l); ah[4 + j] = h; al[4 + j] = l;
    }
    // B fragments: packed, coalesced 1KB per wave per load
    #pragma unroll
    for (int t = 0; t < 4; ++t) {
      short8 bhv = bhp[(kb * 4 + t) * 64];
      short8 blv = blp[(kb * 4 + t) * 64];
      acc[t] = __builtin_amdgcn_mfma_f32_16x16x32_bf16(ah, bhv, acc[t], 0, 0, 0);
      acc[t] = __builtin_amdgcn_mfma_f32_16x16x32_bf16(ah, blv, acc[t], 0, 0, 0);
      acc[t] = __builtin_amdgcn_mfma_f32_16x16x32_bf16(al, bhv, acc[t], 0, 0, 0);
    }
  }

  // write per-wave partials: C/D layout col(way) = lane&15, row(q) = kgrp*4 + r
  #pragma unroll
  for (int t = 0; t < 4; ++t)
    #pragma unroll
    for (int r = 0; r < 4; ++r)
      Sp[wv][kgrp * 4 + r][t * 16 + lrow] = acc[t][r];
  __syncthreads();

  // reduce 8 K-slices, apply 2*dot - pnorm
  for (int i = tid; i < QT * N_WAY; i += 512) {
    int q = i >> 6, w = i & 63;
    float s = 0.f;
    #pragma unroll
    for (int v = 0; v < 8; ++v) s += Sp[v][q][w];
    So[q][w] = 2.f * s - pnorm[w];
  }
  __syncthreads();

  // fused log-softmax + argmax: wave 0, all 64 lanes (16 q x 4 way-quarters)
  if (tid < 64) {
    const int q = lane & 15;
    const int wq = lane >> 4;       // way quarter: ways wq*16 .. wq*16+15
    const int label = qb >> 6;
    float m = -INFINITY; int arg = 0;
    #pragma unroll
    for (int i = 0; i < 16; ++i) {
      int w = wq * 16 + i;
      float v = So[q][w];
      if (v > m) { m = v; arg = w; }
    }
    #pragma unroll
    for (int off = 16; off < 64; off <<= 1) {
      float om = __shfl_xor(m, off);
      int oa = __shfl_xor(arg, off);
      if (om > m || (om == m && oa < arg)) { m = om; arg = oa; }
    }
    float sum = 0.f;
    #pragma unroll
    for (int i = 0; i < 16; ++i) sum += expf(So[q][wq * 16 + i] - m);
    sum += __shfl_xor(sum, 16);
    sum += __shfl_xor(sum, 32);

    float lossq = 0.f, corr = 0.f;
    if (lane < 16) {
      lossq = m + logf(sum) - So[q][label];
      corr = (arg == label) ? 1.f : 0.f;
    }
    #pragma unroll
    for (int off = 8; off > 0; off >>= 1) {
      lossq += __shfl_down(lossq, off);
      corr  += __shfl_down(corr, off);
    }
    if (lane == 0) {
      atomicAdd(&accs[0], lossq);
      atomicAdd(&accs[1], corr);
      __threadfence();
      unsigned old = atomicAdd(cnt, 1u);
      if (old == (unsigned)(gridDim.x - 1)) {  // last block finalizes
        float l = atomicAdd(&accs[0], 0.0f);
        float c = atomicAdd(&accs[1], 0.0f);
        out[0] = l * (1.0f / (float)N_QUERIES);
        out[1] = c * (100.0f / (float)N_QUERIES);
      }
    }
  }
}

extern "C" void kernel_launch(void* const* d_in, const int* in_sizes, int n_in,
                              void* d_out, int out_size, void* d_ws, size_t ws_size,
                              hipStream_t stream) {
  (void)in_sizes; (void)n_in; (void)out_size; (void)ws_size;
  const float* x = (const float*)d_in[0];
  float* out = (float*)d_out;

  // ws layout
  unsigned short* phi = (unsigned short*)d_ws;                  // 64*1024 u16 packed
  unsigned short* plo = phi + N_WAY * DIM;                      // 64*1024 u16 packed
  float* pnorm = (float*)(plo + N_WAY * DIM);                   // 64 f32
  float* accs  = pnorm + N_WAY;                                 // 2 f32
  unsigned* cnt = (unsigned*)(accs + 2);                        // 1 u32

  hipLaunchKernelGGL(proto_kernel, dim3(N_WAY), dim3(256), 0, stream,
                     x, phi, plo, pnorm, accs, cnt);
  hipLaunchKernelGGL(gemm_kernel, dim3(GEMM_BLOCKS), dim3(512), 0, stream,
                     x, phi, plo, pnorm, accs, cnt, out);
}